// Round 7
// baseline (297.695 us; speedup 1.0000x reference)
//
#include <hip/hip_runtime.h>
#include <hip/hip_bf16.h>
#include <math.h>

// GAT forward, N=4096, nfeat=512, nhid=64, nheads=8, nout=56, f32 in/out.
// Split-bf16 (hi+lo, 3 products) MFMA for all big GEMMs.
// R7 vs R6 (R6 crashed - 512-thr attn restructure reverted to R5-proven shell):
//  - attn3 shell identical to R5 (256 thr, 4 waves x 16 rows, NCHUNK split,
//    global_load_lds double-buffered staging, round-half-up split, 3 MFMAs).
//  - NEW: exp eliminated from inner loop. w = exp2(leakyrelu(S1+S2)) with
//    S pre-scaled by log2e factorizes: S1+S2>0 ? E1[i]*E2[j] : F1[i]*F2[j]
//    where E=2^S, F=2^(0.2S) precomputed per row/col in producers; the branch
//    test is E1*E2>1. Inner loop: 2 muls + 2 cndmask + den add per value,
//    ZERO transcendentals (was 1 quarter-rate v_exp each).
//  - prep (pack_adj+conv_x+conv_wt) and mid (zred+l2prep) fusions kept.
// Workspace ~28.8 MB.

#define GN 4096
#define GNH 8
#define LOG2E 1.4426950408889634f

typedef __bf16 bf16x8 __attribute__((ext_vector_type(8)));
typedef float f32x4 __attribute__((ext_vector_type(4)));

#if defined(__has_builtin)
#if __has_builtin(__builtin_amdgcn_exp2f)
#define FAST_EXP2(x) __builtin_amdgcn_exp2f(x)
#endif
#if __has_builtin(__builtin_amdgcn_perm)
#define FAST_PERM(a, b, s) __builtin_amdgcn_perm((a), (b), (s))
#endif
#endif
#ifndef FAST_EXP2
#define FAST_EXP2(x) __expf((x)*0.6931471805599453f)
#endif
#ifndef FAST_PERM
__device__ inline unsigned FAST_PERM(unsigned a, unsigned b, unsigned) {
    return (a & 0xFFFF0000u) | (b >> 16);
}
#endif

__device__ inline void bf16split(float v, unsigned short& hi, unsigned short& lo) {
    __hip_bfloat16 h = __float2bfloat16(v);
    float hb = __bfloat162float(h);
    __hip_bfloat16 l = __float2bfloat16(v - hb);
    hi = *(unsigned short*)&h;
    lo = *(unsigned short*)&l;
}

// round-half-up hi/lo split + pack two values into (hi-pack, lo-pack) u32s
// result: low 16 = value0's bf16, high 16 = value1's bf16
__device__ inline void split_pack2(float w0, float w1, unsigned& hp, unsigned& lp) {
    unsigned u0 = __float_as_uint(w0) + 0x8000u;
    unsigned u1 = __float_as_uint(w1) + 0x8000u;
    float l0 = w0 - __uint_as_float(u0 & 0xFFFF0000u);
    float l1 = w1 - __uint_as_float(u1 & 0xFFFF0000u);
    hp = FAST_PERM(u1, u0, 0x07060302u);             // [u1.b3,u1.b2,u0.b3,u0.b2]
    lp = FAST_PERM(__float_as_uint(l1), __float_as_uint(l0), 0x07060302u);
}

// Fused prep: [0,16384) pack_adj | [16384,18432) conv_x | [18432,18496) conv_wt
__global__ __launch_bounds__(256) void prep(const int* __restrict__ adj,
                                            const float* __restrict__ x,
                                            const float* __restrict__ Ws,
                                            unsigned long long* __restrict__ adjb,
                                            unsigned short* __restrict__ xh,
                                            unsigned short* __restrict__ xl,
                                            unsigned short* __restrict__ wth,
                                            unsigned short* __restrict__ wtl) {
    const int b = blockIdx.x;
    if (b < 16384) {
        const int wv = threadIdx.x >> 6, lane = threadIdx.x & 63;
        const size_t ebase = ((size_t)b * 4 + wv) * 256;
        unsigned long long m[4];
        #pragma unroll
        for (int e = 0; e < 4; ++e)
            m[e] = __ballot(adj[ebase + e * 64 + lane] > 0);
        if (lane == 0) {
            #pragma unroll
            for (int e = 0; e < 4; ++e) adjb[(ebase >> 6) + e] = m[e];
        }
    } else if (b < 18432) {
        int gid = (b - 16384) * 256 + threadIdx.x;   // over 4096*512/4
        float4 v = *(const float4*)&x[(size_t)gid * 4];
        unsigned hp[2], lp[2];
        split_pack2(v.x, v.y, hp[0], lp[0]);
        split_pack2(v.z, v.w, hp[1], lp[1]);
        *(uint2*)&xh[(size_t)gid * 4] = *(uint2*)hp;
        *(uint2*)&xl[(size_t)gid * 4] = *(uint2*)lp;
    } else {
        int b2 = b - 18432;
        int head = b2 >> 3;
        int k0 = (b2 & 7) * 64;
        for (int it = 0; it < 16; ++it) {
            int e = threadIdx.x + it * 256;          // over 64x64
            int k = k0 + (e >> 6), f = e & 63;
            unsigned short h, l;
            bf16split(Ws[((size_t)head * 512 + k) * 64 + f], h, l);
            wth[(size_t)head * 32768 + f * 512 + k] = h;
            wtl[(size_t)head * 32768 + f * 512 + k] = l;
        }
    }
}

// h = x @ Ws[head]; epilogue emits swizzled bf16 image (hi/lo) + per-row
// attention factors ef1={2^S1, 2^(0.2 S1)}, ef2 likewise (S = log2e-scaled).
// grid (8 heads, 64 i-tiles), 256 thr.
// Image unit (f, c) at shorts offset f*64 + ((c^(f&7))*8), elements j=c*8+q.
__global__ __launch_bounds__(256) void gemm_fused(const unsigned short* __restrict__ xh,
                                                  const unsigned short* __restrict__ xl,
                                                  const unsigned short* __restrict__ wth,
                                                  const unsigned short* __restrict__ wtl,
                                                  const float* __restrict__ As,
                                                  unsigned short* __restrict__ imgh,
                                                  unsigned short* __restrict__ imgl,
                                                  float2* __restrict__ ef1,
                                                  float2* __restrict__ ef2) {
    __shared__ __align__(16) unsigned short smem[4][64 * 72];
    unsigned short* xAh = smem[0];
    unsigned short* xAl = smem[1];
    unsigned short* wBh = smem[2];
    unsigned short* wBl = smem[3];
    const int tid = threadIdx.x;
    const int head = blockIdx.x;
    const int itile = blockIdx.y;
    const int i0 = itile * 64;
    const unsigned short* wh = wth + (size_t)head * 32768;
    const unsigned short* wl = wtl + (size_t)head * 32768;
    const int lane = tid & 63, wv_ = tid >> 6;
    const int mi = (wv_ & 1) * 32, fi = (wv_ >> 1) * 32;
    const int row = lane & 15, quad = lane >> 4;
    f32x4 acc[2][2] = {};
    const int e0 = tid * 8, e1 = e0 + 2048;
    const int r0 = e0 >> 6, o0 = e0 & 63, r1 = e1 >> 6, o1 = e1 & 63;
    for (int k0 = 0; k0 < 512; k0 += 64) {
        __syncthreads();
        *(uint4*)&xAh[r0 * 72 + o0] = *(const uint4*)&xh[(size_t)(i0 + r0) * 512 + k0 + o0];
        *(uint4*)&xAh[r1 * 72 + o1] = *(const uint4*)&xh[(size_t)(i0 + r1) * 512 + k0 + o1];
        *(uint4*)&xAl[r0 * 72 + o0] = *(const uint4*)&xl[(size_t)(i0 + r0) * 512 + k0 + o0];
        *(uint4*)&xAl[r1 * 72 + o1] = *(const uint4*)&xl[(size_t)(i0 + r1) * 512 + k0 + o1];
        *(uint4*)&wBh[r0 * 72 + o0] = *(const uint4*)&wh[(size_t)r0 * 512 + k0 + o0];
        *(uint4*)&wBh[r1 * 72 + o1] = *(const uint4*)&wh[(size_t)r1 * 512 + k0 + o1];
        *(uint4*)&wBl[r0 * 72 + o0] = *(const uint4*)&wl[(size_t)r0 * 512 + k0 + o0];
        *(uint4*)&wBl[r1 * 72 + o1] = *(const uint4*)&wl[(size_t)r1 * 512 + k0 + o1];
        __syncthreads();
        #pragma unroll
        for (int ks = 0; ks < 2; ++ks) {
            const int ko = ks * 32 + quad * 8;
            bf16x8 ah[2], al[2], bh[2], bl[2];
            #pragma unroll
            for (int t = 0; t < 2; ++t) {
                ah[t] = *(const bf16x8*)&xAh[(mi + t * 16 + row) * 72 + ko];
                al[t] = *(const bf16x8*)&xAl[(mi + t * 16 + row) * 72 + ko];
                bh[t] = *(const bf16x8*)&wBh[(fi + t * 16 + row) * 72 + ko];
                bl[t] = *(const bf16x8*)&wBl[(fi + t * 16 + row) * 72 + ko];
            }
            #pragma unroll
            for (int mt = 0; mt < 2; ++mt)
                #pragma unroll
                for (int nt = 0; nt < 2; ++nt) {
                    acc[mt][nt] = __builtin_amdgcn_mfma_f32_16x16x32_bf16(ah[mt], bh[nt], acc[mt][nt], 0, 0, 0);
                    acc[mt][nt] = __builtin_amdgcn_mfma_f32_16x16x32_bf16(al[mt], bh[nt], acc[mt][nt], 0, 0, 0);
                    acc[mt][nt] = __builtin_amdgcn_mfma_f32_16x16x32_bf16(ah[mt], bl[nt], acc[mt][nt], 0, 0, 0);
                }
        }
    }
    // ---- fused epilogue ----
    __syncthreads();
    float* ht = (float*)&smem[0][0];                 // 64 x 68 f32 (17.4 KB, fits)
    #pragma unroll
    for (int mt = 0; mt < 2; ++mt)
        #pragma unroll
        for (int nt = 0; nt < 2; ++nt)
            #pragma unroll
            for (int r = 0; r < 4; ++r)
                ht[(mi + mt * 16 + quad * 4 + r) * 68 + fi + nt * 16 + row] = acc[mt][nt][r];
    __syncthreads();
    {   // per-row factors: thread t -> row t>>2, seg (t&3)*16
        const int rrow = tid >> 2, seg = (tid & 3) * 16;
        const float* ah = As + head * 128;
        float p1 = 0.f, p2 = 0.f;
        #pragma unroll
        for (int c = 0; c < 16; ++c) {
            float v = ht[rrow * 68 + seg + c];
            p1 += v * ah[seg + c];
            p2 += v * ah[64 + seg + c];
        }
        p1 += __shfl_xor(p1, 1); p1 += __shfl_xor(p1, 2);
        p2 += __shfl_xor(p2, 1); p2 += __shfl_xor(p2, 2);
        if ((tid & 3) == 0) {
            float t1 = p1 * LOG2E, t2 = p2 * LOG2E;
            ef1[head * GN + i0 + rrow] = make_float2(FAST_EXP2(t1), FAST_EXP2(0.2f * t1));
            ef2[head * GN + i0 + rrow] = make_float2(FAST_EXP2(t2), FAST_EXP2(0.2f * t2));
        }
    }
    {   // swizzled image emit
        const int f = tid >> 2;
        size_t base = ((size_t)head * 64 + itile) * 4096 + (size_t)f * 64;
        #pragma unroll
        for (int p = 0; p < 2; ++p) {
            int c = (tid & 3) * 2 + p;
            unsigned hp[4], lp[4];
            #pragma unroll
            for (int pp = 0; pp < 4; ++pp)
                split_pack2(ht[(c * 8 + 2 * pp) * 68 + f], ht[(c * 8 + 2 * pp + 1) * 68 + f],
                            hp[pp], lp[pp]);
            int off = (c ^ (f & 7)) * 8;
            *(uint4*)&imgh[base + off] = *(uint4*)hp;
            *(uint4*)&imgl[base + off] = *(uint4*)lp;
        }
    }
}

// Fused masked-softmax attention; w built in A-frag registers from
// precomputed row/col factors: w = (E1*E2 > 1) ? E1*E2 : F1*F2, masked.
// 256 thr = 4 waves x 16 rows (mt=1, nt=4); tile 64 rows x 64 j.
// global_load_lds async staging of pre-swizzled image; double-buffered.
// grid (64 i-tiles, GNH*NCHUNK or NCHUNK). Raw partial O + denom per slice.
template <int NCHUNK>
__global__ __launch_bounds__(256, 4) void attn3(const unsigned short* __restrict__ imgh,
                                                const unsigned short* __restrict__ imgl,
                                                const float2* __restrict__ ef1g,
                                                const float2* __restrict__ ef2g,
                                                const unsigned long long* __restrict__ adjb,
                                                float* __restrict__ pO,
                                                float* __restrict__ pd) {
    __shared__ __align__(16) unsigned short hb[2][8192];   // [buf][hi 4096 | lo 4096]
    const int tid = threadIdx.x;
    const int lane = tid & 63, wv = tid >> 6;
    const int row = lane & 15, quad = lane >> 4;
    const int head = blockIdx.y / NCHUNK;
    const int chunk = blockIdx.y % NCHUNK;
    const int i0 = blockIdx.x * 64;
    const int jb = chunk * (GN / NCHUNK);
    const int njt = (GN / NCHUNK) / 64;
    const int jt0 = jb >> 6;
    const unsigned short* ih = imgh + (size_t)head * (64 * GN);
    const unsigned short* il = imgl + (size_t)head * (64 * GN);
    const float2* ef2h = ef2g + head * GN;
    const int gr = i0 + wv * 16 + row;
    const float2 f1v = ef1g[head * GN + gr];
    const float E1 = f1v.x, F1 = f1v.y;
    const unsigned long long* adjr = adjb + (size_t)gr * 64 + jt0;

    f32x4 acc[4] = {};
    float den = 0.f;

    #define STAGE(buf, T)                                                                  \
        do {                                                                               \
            const unsigned short* gh_ = ih + (size_t)(T) * 4096;                           \
            const unsigned short* gl_ = il + (size_t)(T) * 4096;                           \
            _Pragma("unroll")                                                              \
            for (int c_ = 0; c_ < 2; ++c_)                                                 \
                __builtin_amdgcn_global_load_lds(                                          \
                    (const __attribute__((address_space(1))) unsigned int*)(gh_ + c_ * 2048 + tid * 8), \
                    (__attribute__((address_space(3))) unsigned int*)&hb[buf][c_ * 2048 + tid * 8],     \
                    16, 0, 0);                                                             \
            _Pragma("unroll")                                                              \
            for (int c_ = 0; c_ < 2; ++c_)                                                 \
                __builtin_amdgcn_global_load_lds(                                          \
                    (const __attribute__((address_space(1))) unsigned int*)(gl_ + c_ * 2048 + tid * 8), \
                    (__attribute__((address_space(3))) unsigned int*)&hb[buf][4096 + c_ * 2048 + tid * 8], \
                    16, 0, 0);                                                             \
        } while (0)

    STAGE(0, jt0);
    for (int jt = 0; jt < njt; ++jt) {
        __syncthreads();                             // drains loads into buf cur
        const int cur = jt & 1;
        if (jt + 1 < njt) STAGE(cur ^ 1, jt0 + jt + 1);
        const int j0 = jb + jt * 64;
        const unsigned long long wd = adjr[jt];
        #pragma unroll
        for (int ks = 0; ks < 2; ++ks) {
            const int kb = ks * 32 + quad * 8;
            const unsigned bits = (unsigned)(wd >> kb) & 0xFFu;
            union { unsigned u[4]; bf16x8 v; } hfr, lfr;
            #pragma unroll
            for (int p = 0; p < 4; ++p) {
                float4 v = *(const float4*)(ef2h + j0 + kb + 2 * p);  // {E,F,E,F} for 2 j's
                float wp0 = E1 * v.x, wn0 = F1 * v.y;
                float w0 = ((bits >> (2 * p)) & 1u) ? (wp0 > 1.f ? wp0 : wn0) : 0.f;
                float wp1 = E1 * v.z, wn1 = F1 * v.w;
                float w1 = ((bits >> (2 * p + 1)) & 1u) ? (wp1 > 1.f ? wp1 : wn1) : 0.f;
                den += w0 + w1;
                split_pack2(w0, w1, hfr.u[p], lfr.u[p]);
            }
            #pragma unroll
            for (int nt = 0; nt < 4; ++nt) {
                const int f = nt * 16 + row;
                const int off = f * 64 + (((ks * 4 + quad) ^ (f & 7)) * 8);
                bf16x8 bh = *(const bf16x8*)&hb[cur][off];
                bf16x8 bl = *(const bf16x8*)&hb[cur][4096 + off];
                acc[nt] = __builtin_amdgcn_mfma_f32_16x16x32_bf16(hfr.v, bh, acc[nt], 0, 0, 0);
                acc[nt] = __builtin_amdgcn_mfma_f32_16x16x32_bf16(lfr.v, bh, acc[nt], 0, 0, 0);
                acc[nt] = __builtin_amdgcn_mfma_f32_16x16x32_bf16(hfr.v, bl, acc[nt], 0, 0, 0);
            }
        }
    }
    #undef STAGE
    // row denominators: lanes {l, l^16, l^32, l^48} share a row
    den += __shfl_xor(den, 16);
    den += __shfl_xor(den, 32);
    float* o = pO + (size_t)blockIdx.y * (GN * 64);
    #pragma unroll
    for (int r = 0; r < 4; ++r) {
        const int grow = i0 + wv * 16 + quad * 4 + r;
        #pragma unroll
        for (int nt = 0; nt < 4; ++nt)
            o[(size_t)grow * 64 + nt * 16 + row] = acc[nt][r];
    }
    if (lane < 16) pd[blockIdx.y * GN + i0 + wv * 16 + lane] = den;
}

// Fused zred2 + l2prep: combine L1 partials -> z (LDS only) -> h2 = z @ W_out
// -> ef1b/ef2b factors + swizzled bf16 image. grid 64 blocks, 256 thr.
__global__ __launch_bounds__(256) void mid(const float* __restrict__ pO,
                                           const float* __restrict__ pd,
                                           const float* __restrict__ Wo,
                                           const float* __restrict__ ao,
                                           unsigned short* __restrict__ img2h,
                                           unsigned short* __restrict__ img2l,
                                           float2* __restrict__ ef1b,
                                           float2* __restrict__ ef2b) {
    __shared__ __align__(16) float zt[64 * 68];
    __shared__ float Wl[64 * 57];
    __shared__ float invd[8][64];
    const int tid = threadIdx.x;
    const int i0 = blockIdx.x * 64;
    for (int idx = tid; idx < 64 * 56; idx += 256) {
        int k = idx / 56, c = idx - k * 56;
        Wl[k * 57 + c] = Wo[idx];
    }
    for (int idx = tid; idx < 512; idx += 256) {
        int hd = idx >> 6, r = idx & 63;
        invd[hd][r] = 1.f / (pd[(2 * hd) * GN + i0 + r] + pd[(2 * hd + 1) * GN + i0 + r]);
    }
    __syncthreads();
    #pragma unroll
    for (int it = 0; it < 16; ++it) {                // z fill: 4096 elems
        int e = it * 256 + tid;
        int r = e >> 6, f = e & 63;
        size_t base = (size_t)(i0 + r) * 64 + f;
        float s = 0.f;
        #pragma unroll
        for (int hd = 0; hd < GNH; ++hd) {
            float o = pO[(size_t)(2 * hd) * (GN * 64) + base] +
                      pO[(size_t)(2 * hd + 1) * (GN * 64) + base];
            float v = o * invd[hd][r];
            s += v > 0.f ? v : FAST_EXP2(v * LOG2E) - 1.f;
        }
        zt[r * 68 + f] = s * 0.125f;
    }
    __syncthreads();
    const int rrow = tid >> 2, seg = (tid & 3) * 16;
    float hreg[16];
    #pragma unroll
    for (int c = 0; c < 16; ++c) hreg[c] = 0.f;
    for (int k0 = 0; k0 < 64; k0 += 4) {
        float4 zv = *(const float4*)&zt[rrow * 68 + k0];
        #pragma unroll
        for (int c = 0; c < 16; ++c) {
            int col = seg + c;
            if (col < 56)
                hreg[c] += zv.x * Wl[k0 * 57 + col] + zv.y * Wl[(k0 + 1) * 57 + col] +
                           zv.z * Wl[(k0 + 2) * 57 + col] + zv.w * Wl[(k0 + 3) * 57 + col];
        }
    }
    {   // row/col factors for layer 2
        float p1 = 0.f, p2 = 0.f;
        #pragma unroll
        for (int c = 0; c < 16; ++c) {
            int col = seg + c;
            if (col < 56) {
                p1 += hreg[c] * ao[col];
                p2 += hreg[c] * ao[56 + col];
            }
        }
        p1 += __shfl_xor(p1, 1); p1 += __shfl_xor(p1, 2);
        p2 += __shfl_xor(p2, 1); p2 += __shfl_xor(p2, 2);
        if ((tid & 3) == 0) {
            float t1 = p1 * LOG2E, t2 = p2 * LOG2E;
            ef1b[i0 + rrow] = make_float2(FAST_EXP2(t1), FAST_EXP2(0.2f * t1));
            ef2b[i0 + rrow] = make_float2(FAST_EXP2(t2), FAST_EXP2(0.2f * t2));
        }
    }
    __syncthreads();
    #pragma unroll
    for (int c = 0; c < 16; ++c) zt[rrow * 68 + seg + c] = (seg + c < 56) ? hreg[c] : 0.f;
    __syncthreads();
    {   // swizzled image emit (single head)
        const int f = tid >> 2;
        size_t base = (size_t)blockIdx.x * 4096 + (size_t)f * 64;
        #pragma unroll
        for (int p = 0; p < 2; ++p) {
            int c = (tid & 3) * 2 + p;
            unsigned hp[4], lp[4];
            #pragma unroll
            for (int pp = 0; pp < 4; ++pp)
                split_pack2(zt[(c * 8 + 2 * pp) * 68 + f], zt[(c * 8 + 2 * pp + 1) * 68 + f],
                            hp[pp], lp[pp]);
            int off = (c ^ (f & 7)) * 8;
            *(uint4*)&img2h[base + off] = *(uint4*)hp;
            *(uint4*)&img2l[base + off] = *(uint4*)lp;
        }
    }
}

// combine 16 j-chunk partials, /denom, elu, softmax(56) -> out
__global__ __launch_bounds__(256) void fink2(const float* __restrict__ pO,
                                             const float* __restrict__ pd,
                                             float* __restrict__ out) {
    const int lane = threadIdx.x & 63;
    const int w = threadIdx.x >> 6;
    const int i = blockIdx.x * 4 + w;
    float o = 0.f, d = 0.f;
    #pragma unroll
    for (int c = 0; c < 16; ++c) d += pd[c * GN + i];
    if (lane < 56) {
        #pragma unroll
        for (int c = 0; c < 16; ++c) o += pO[(size_t)c * (GN * 64) + (size_t)i * 64 + lane];
    }
    float v = -1e30f;
    if (lane < 56) {
        float t = o / d;
        v = t > 0.f ? t : expm1f(t);
    }
    float m = v;
    #pragma unroll
    for (int off = 32; off; off >>= 1) m = fmaxf(m, __shfl_down(m, off));
    m = __shfl(m, 0);
    float p = (lane < 56) ? __expf(v - m) : 0.f;
    float s = p;
    #pragma unroll
    for (int off = 32; off; off >>= 1) s += __shfl_down(s, off);
    s = __shfl(s, 0);
    if (lane < 56) out[(size_t)i * 56 + lane] = p / s;
}

extern "C" void kernel_launch(void* const* d_in, const int* in_sizes, int n_in,
                              void* d_out, int out_size, void* d_ws, size_t ws_size,
                              hipStream_t stream) {
    const float* x    = (const float*)d_in[0];
    const int*   adj  = (const int*)d_in[1];
    const float* Ws   = (const float*)d_in[2];
    const float* As   = (const float*)d_in[3];
    const float* Wo   = (const float*)d_in[4];
    const float* ao   = (const float*)d_in[5];
    float* out = (float*)d_out;

    char* ws = (char*)d_ws;
    unsigned long long* adjb = (unsigned long long*)(ws + 0);           // 2 MB
    unsigned short* img1h = (unsigned short*)(ws + 2097152);            // 4 MB
    unsigned short* img1l = (unsigned short*)(ws + 6291456);            // 4 MB
    float* pO    = (float*)(ws + 10485760);                             // 16 MB (slices)
    unsigned short* x_hi = (unsigned short*)(ws + 18874368);            // 4 MB (inside pO, pre-attn only)
    unsigned short* x_lo = (unsigned short*)(ws + 23068672);            // 4 MB (inside pO, pre-attn only)
    float* pd    = (float*)(ws + 27262976);                             // 256 KB (shared L1/L2)
    float2* ef1  = (float2*)(ws + 27525120);                            // 256 KB
    float2* ef2  = (float2*)(ws + 27787264);                            // 256 KB
    unsigned short* img2h = (unsigned short*)(ws + 28049408);           // 512 KB
    unsigned short* img2l = (unsigned short*)(ws + 28573696);           // 512 KB
    float2* ef1b = (float2*)(ws + 29097984);                            // 32 KB
    float2* ef2b = (float2*)(ws + 29130752);                            // 32 KB
    unsigned short* WT_hi = (unsigned short*)(ws + 29163520);           // 512 KB
    unsigned short* WT_lo = (unsigned short*)(ws + 29687808);           // 512 KB
    // total 30212096 B ~= 28.8 MB

    prep<<<18496, 256, 0, stream>>>(adj, x, Ws, adjb, x_hi, x_lo, WT_hi, WT_lo);
    gemm_fused<<<dim3(8, 64), 256, 0, stream>>>(x_hi, x_lo, WT_hi, WT_lo, As,
                                                img1h, img1l, ef1, ef2);
    attn3<2><<<dim3(64, 16), 256, 0, stream>>>(img1h, img1l, ef1, ef2, adjb, pO, pd);
    mid<<<64, 256, 0, stream>>>(pO, pd, Wo, ao, img2h, img2l, ef1b, ef2b);
    attn3<16><<<dim3(64, 16), 256, 0, stream>>>(img2h, img2l, ef1b, ef2b, adjb, pO, pd);
    fink2<<<1024, 256, 0, stream>>>(pO, pd, out);
}

// Round 8
// 284.555 us; speedup vs baseline: 1.0462x; 1.0462x over previous
//
#include <hip/hip_runtime.h>
#include <hip/hip_bf16.h>
#include <math.h>

// GAT forward, N=4096, nfeat=512, nhid=64, nheads=8, nout=56, f32 in/out.
// Split-bf16 (hi+lo, 3 products) MFMA for all big GEMMs.
// R8 vs R7 (R7 attn latency-bound: ef2 loads in-loop coupled with staging via
// in-order vmcnt; also nt=4 row-split makes every wave read the full LDS tile
// -> 41us hidden LDS floor):
//  - attn5: 128-thr / 2-wave blocks, wave = 32 rows (mt=2) x 64 f (nt=4),
//    32-j tiles (8KB staged, 16KB LDS) -> 8 blocks/CU; LDS reads halved.
//  - software pipeline: ef2+adj prefetched into REGISTERS one tile ahead,
//    issued BEFORE STAGE(next) so their vmcnt wait (4) never drains staging;
//    MFMA phase consumes only previously-prefetched w fragments (zero loads).
//  - 32-j image swizzle f*32 + ((c ^ ((f>>1)&3))*8) - bank-conflict-free.
//  - producers (gemm_fused / mid) emit the new 32-j tile image; all else R7.
// Workspace ~28.8 MB.

#define GN 4096
#define GNH 8
#define LOG2E 1.4426950408889634f

typedef __bf16 bf16x8 __attribute__((ext_vector_type(8)));
typedef float f32x4 __attribute__((ext_vector_type(4)));

#if defined(__has_builtin)
#if __has_builtin(__builtin_amdgcn_exp2f)
#define FAST_EXP2(x) __builtin_amdgcn_exp2f(x)
#endif
#if __has_builtin(__builtin_amdgcn_perm)
#define FAST_PERM(a, b, s) __builtin_amdgcn_perm((a), (b), (s))
#endif
#endif
#ifndef FAST_EXP2
#define FAST_EXP2(x) __expf((x)*0.6931471805599453f)
#endif
#ifndef FAST_PERM
__device__ inline unsigned FAST_PERM(unsigned a, unsigned b, unsigned) {
    return (a & 0xFFFF0000u) | (b >> 16);
}
#endif

__device__ inline void bf16split(float v, unsigned short& hi, unsigned short& lo) {
    __hip_bfloat16 h = __float2bfloat16(v);
    float hb = __bfloat162float(h);
    __hip_bfloat16 l = __float2bfloat16(v - hb);
    hi = *(unsigned short*)&h;
    lo = *(unsigned short*)&l;
}

// round-half-up hi/lo split + pack two values into (hi-pack, lo-pack) u32s
// result: low 16 = value0's bf16, high 16 = value1's bf16
__device__ inline void split_pack2(float w0, float w1, unsigned& hp, unsigned& lp) {
    unsigned u0 = __float_as_uint(w0) + 0x8000u;
    unsigned u1 = __float_as_uint(w1) + 0x8000u;
    float l0 = w0 - __uint_as_float(u0 & 0xFFFF0000u);
    float l1 = w1 - __uint_as_float(u1 & 0xFFFF0000u);
    hp = FAST_PERM(u1, u0, 0x07060302u);             // [u1.b3,u1.b2,u0.b3,u0.b2]
    lp = FAST_PERM(__float_as_uint(l1), __float_as_uint(l0), 0x07060302u);
}

// Fused prep: [0,16384) pack_adj | [16384,18432) conv_x | [18432,18496) conv_wt
__global__ __launch_bounds__(256) void prep(const int* __restrict__ adj,
                                            const float* __restrict__ x,
                                            const float* __restrict__ Ws,
                                            unsigned long long* __restrict__ adjb,
                                            unsigned short* __restrict__ xh,
                                            unsigned short* __restrict__ xl,
                                            unsigned short* __restrict__ wth,
                                            unsigned short* __restrict__ wtl) {
    const int b = blockIdx.x;
    if (b < 16384) {
        const int wv = threadIdx.x >> 6, lane = threadIdx.x & 63;
        const size_t ebase = ((size_t)b * 4 + wv) * 256;
        unsigned long long m[4];
        #pragma unroll
        for (int e = 0; e < 4; ++e)
            m[e] = __ballot(adj[ebase + e * 64 + lane] > 0);
        if (lane == 0) {
            #pragma unroll
            for (int e = 0; e < 4; ++e) adjb[(ebase >> 6) + e] = m[e];
        }
    } else if (b < 18432) {
        int gid = (b - 16384) * 256 + threadIdx.x;   // over 4096*512/4
        float4 v = *(const float4*)&x[(size_t)gid * 4];
        unsigned hp[2], lp[2];
        split_pack2(v.x, v.y, hp[0], lp[0]);
        split_pack2(v.z, v.w, hp[1], lp[1]);
        *(uint2*)&xh[(size_t)gid * 4] = *(uint2*)hp;
        *(uint2*)&xl[(size_t)gid * 4] = *(uint2*)lp;
    } else {
        int b2 = b - 18432;
        int head = b2 >> 3;
        int k0 = (b2 & 7) * 64;
        for (int it = 0; it < 16; ++it) {
            int e = threadIdx.x + it * 256;          // over 64x64
            int k = k0 + (e >> 6), f = e & 63;
            unsigned short h, l;
            bf16split(Ws[((size_t)head * 512 + k) * 64 + f], h, l);
            wth[(size_t)head * 32768 + f * 512 + k] = h;
            wtl[(size_t)head * 32768 + f * 512 + k] = l;
        }
    }
}

// h = x @ Ws[head]; epilogue emits swizzled bf16 image (32-j tiles, hi/lo) +
// per-row attention factors ef = {2^S, 2^(0.2 S)} (S = log2e-scaled score).
// grid (8 heads, 64 i-tiles), 256 thr.
// Image: per 32-j tile (2048 shorts), unit (f, c) at f*32 + ((c^((f>>1)&3))*8)
// holding elements j = c*8 + q, c in 0..3.
__global__ __launch_bounds__(256) void gemm_fused(const unsigned short* __restrict__ xh,
                                                  const unsigned short* __restrict__ xl,
                                                  const unsigned short* __restrict__ wth,
                                                  const unsigned short* __restrict__ wtl,
                                                  const float* __restrict__ As,
                                                  unsigned short* __restrict__ imgh,
                                                  unsigned short* __restrict__ imgl,
                                                  float2* __restrict__ ef1,
                                                  float2* __restrict__ ef2) {
    __shared__ __align__(16) unsigned short smem[4][64 * 72];
    unsigned short* xAh = smem[0];
    unsigned short* xAl = smem[1];
    unsigned short* wBh = smem[2];
    unsigned short* wBl = smem[3];
    const int tid = threadIdx.x;
    const int head = blockIdx.x;
    const int itile = blockIdx.y;
    const int i0 = itile * 64;
    const unsigned short* wh = wth + (size_t)head * 32768;
    const unsigned short* wl = wtl + (size_t)head * 32768;
    const int lane = tid & 63, wv_ = tid >> 6;
    const int mi = (wv_ & 1) * 32, fi = (wv_ >> 1) * 32;
    const int row = lane & 15, quad = lane >> 4;
    f32x4 acc[2][2] = {};
    const int e0 = tid * 8, e1 = e0 + 2048;
    const int r0 = e0 >> 6, o0 = e0 & 63, r1 = e1 >> 6, o1 = e1 & 63;
    for (int k0 = 0; k0 < 512; k0 += 64) {
        __syncthreads();
        *(uint4*)&xAh[r0 * 72 + o0] = *(const uint4*)&xh[(size_t)(i0 + r0) * 512 + k0 + o0];
        *(uint4*)&xAh[r1 * 72 + o1] = *(const uint4*)&xh[(size_t)(i0 + r1) * 512 + k0 + o1];
        *(uint4*)&xAl[r0 * 72 + o0] = *(const uint4*)&xl[(size_t)(i0 + r0) * 512 + k0 + o0];
        *(uint4*)&xAl[r1 * 72 + o1] = *(const uint4*)&xl[(size_t)(i0 + r1) * 512 + k0 + o1];
        *(uint4*)&wBh[r0 * 72 + o0] = *(const uint4*)&wh[(size_t)r0 * 512 + k0 + o0];
        *(uint4*)&wBh[r1 * 72 + o1] = *(const uint4*)&wh[(size_t)r1 * 512 + k0 + o1];
        *(uint4*)&wBl[r0 * 72 + o0] = *(const uint4*)&wl[(size_t)r0 * 512 + k0 + o0];
        *(uint4*)&wBl[r1 * 72 + o1] = *(const uint4*)&wl[(size_t)r1 * 512 + k0 + o1];
        __syncthreads();
        #pragma unroll
        for (int ks = 0; ks < 2; ++ks) {
            const int ko = ks * 32 + quad * 8;
            bf16x8 ah[2], al[2], bh[2], bl[2];
            #pragma unroll
            for (int t = 0; t < 2; ++t) {
                ah[t] = *(const bf16x8*)&xAh[(mi + t * 16 + row) * 72 + ko];
                al[t] = *(const bf16x8*)&xAl[(mi + t * 16 + row) * 72 + ko];
                bh[t] = *(const bf16x8*)&wBh[(fi + t * 16 + row) * 72 + ko];
                bl[t] = *(const bf16x8*)&wBl[(fi + t * 16 + row) * 72 + ko];
            }
            #pragma unroll
            for (int mt = 0; mt < 2; ++mt)
                #pragma unroll
                for (int nt = 0; nt < 2; ++nt) {
                    acc[mt][nt] = __builtin_amdgcn_mfma_f32_16x16x32_bf16(ah[mt], bh[nt], acc[mt][nt], 0, 0, 0);
                    acc[mt][nt] = __builtin_amdgcn_mfma_f32_16x16x32_bf16(al[mt], bh[nt], acc[mt][nt], 0, 0, 0);
                    acc[mt][nt] = __builtin_amdgcn_mfma_f32_16x16x32_bf16(ah[mt], bl[nt], acc[mt][nt], 0, 0, 0);
                }
        }
    }
    // ---- fused epilogue ----
    __syncthreads();
    float* ht = (float*)&smem[0][0];                 // 64 x 68 f32 (17.4 KB, fits)
    #pragma unroll
    for (int mt = 0; mt < 2; ++mt)
        #pragma unroll
        for (int nt = 0; nt < 2; ++nt)
            #pragma unroll
            for (int r = 0; r < 4; ++r)
                ht[(mi + mt * 16 + quad * 4 + r) * 68 + fi + nt * 16 + row] = acc[mt][nt][r];
    __syncthreads();
    {   // per-row factors: thread t -> row t>>2, seg (t&3)*16
        const int rrow = tid >> 2, seg = (tid & 3) * 16;
        const float* ah = As + head * 128;
        float p1 = 0.f, p2 = 0.f;
        #pragma unroll
        for (int c = 0; c < 16; ++c) {
            float v = ht[rrow * 68 + seg + c];
            p1 += v * ah[seg + c];
            p2 += v * ah[64 + seg + c];
        }
        p1 += __shfl_xor(p1, 1); p1 += __shfl_xor(p1, 2);
        p2 += __shfl_xor(p2, 1); p2 += __shfl_xor(p2, 2);
        if ((tid & 3) == 0) {
            float t1 = p1 * LOG2E, t2 = p2 * LOG2E;
            ef1[head * GN + i0 + rrow] = make_float2(FAST_EXP2(t1), FAST_EXP2(0.2f * t1));
            ef2[head * GN + i0 + rrow] = make_float2(FAST_EXP2(t2), FAST_EXP2(0.2f * t2));
        }
    }
    {   // swizzled image emit (32-j tiles)
        const int f = tid >> 2;
        #pragma unroll
        for (int p = 0; p < 2; ++p) {
            int c8 = (tid & 3) * 2 + p;              // 0..7: j's = c8*8 + q
            unsigned hp[4], lp[4];
            #pragma unroll
            for (int pp = 0; pp < 4; ++pp)
                split_pack2(ht[(c8 * 8 + 2 * pp) * 68 + f], ht[(c8 * 8 + 2 * pp + 1) * 68 + f],
                            hp[pp], lp[pp]);
            int t32 = c8 >> 2, c = c8 & 3;
            size_t base = ((size_t)head * 128 + itile * 2 + t32) * 2048 + (size_t)f * 32;
            int off = (c ^ ((f >> 1) & 3)) * 8;
            *(uint4*)&imgh[base + off] = *(uint4*)hp;
            *(uint4*)&imgl[base + off] = *(uint4*)lp;
        }
    }
}

// Fused masked-softmax attention, software-pipelined.
// 128 thr = 2 waves; wave = 32 rows (mt=2) x 64 f (nt=4); 32-j tiles.
// w = (E1*E2 > 1 ? E1*E2 : F1*F2) * maskbit, built in A-frag registers from
// factors prefetched into regs ONE TILE AHEAD (issued before STAGE so the
// vmcnt wait never drains the staging queue). grid (64 i-tiles, 16 slices).
template <int NCHUNK>
__global__ __launch_bounds__(128, 4) void attn5(const unsigned short* __restrict__ imgh,
                                                const unsigned short* __restrict__ imgl,
                                                const float2* __restrict__ ef1g,
                                                const float2* __restrict__ ef2g,
                                                const unsigned* __restrict__ adj32,
                                                float* __restrict__ pO,
                                                float* __restrict__ pd) {
    __shared__ __align__(16) unsigned short hb[2][4096];   // [buf][hi 2048 | lo 2048]
    const int tid = threadIdx.x;
    const int lane = tid & 63, wv = tid >> 6;
    const int row = lane & 15, quad = lane >> 4;
    const int head = blockIdx.y / NCHUNK;
    const int chunk = blockIdx.y % NCHUNK;
    const int i0 = blockIdx.x * 64;
    const int jb = chunk * (GN / NCHUNK);
    const int njt = (GN / NCHUNK) / 32;              // 32-j tiles (even: 64 or 8)
    const int t0 = jb >> 5;
    const unsigned short* ih = imgh + (size_t)head * (64 * GN);
    const unsigned short* il = imgl + (size_t)head * (64 * GN);
    const float2* ef2h = ef2g + head * GN;
    const int gr0 = i0 + wv * 32 + row;              // rows gr0 (mt0), gr0+16 (mt1)
    const float2 fa = ef1g[head * GN + gr0];
    const float2 fb = ef1g[head * GN + gr0 + 16];
    const float E1a = fa.x, F1a = fa.y, E1b = fb.x, F1b = fb.y;
    const unsigned* adjr0 = adj32 + (size_t)gr0 * 128 + (jb >> 5);
    const unsigned* adjr1 = adjr0 + 16 * 128;

    union WSet { unsigned u[4]; bf16x8 v; };
    WSet hfA[2], lfA[2], hfB[2], lfB[2];
    f32x4 acc[2][4] = {};
    float den0 = 0.f, den1 = 0.f;
    float4 e[4];
    unsigned aw0, aw1;

    #define LOADT(t)                                                                       \
        do {                                                                               \
            const float2* _b = ef2h + jb + (t) * 32 + quad * 8;                            \
            e[0] = *(const float4*)(_b);     e[1] = *(const float4*)(_b + 2);              \
            e[2] = *(const float4*)(_b + 4); e[3] = *(const float4*)(_b + 6);              \
            aw0 = adjr0[t]; aw1 = adjr1[t];                                                \
        } while (0)

    #define STAGE(buf, T)                                                                  \
        do {                                                                               \
            const unsigned short* gh_ = ih + (size_t)(T) * 2048;                           \
            const unsigned short* gl_ = il + (size_t)(T) * 2048;                           \
            __builtin_amdgcn_global_load_lds(                                              \
                (const __attribute__((address_space(1))) unsigned int*)(gh_ + tid * 8),    \
                (__attribute__((address_space(3))) unsigned int*)&hb[buf][tid * 8], 16, 0, 0); \
            __builtin_amdgcn_global_load_lds(                                              \
                (const __attribute__((address_space(1))) unsigned int*)(gh_ + 1024 + tid * 8), \
                (__attribute__((address_space(3))) unsigned int*)&hb[buf][1024 + tid * 8], 16, 0, 0); \
            __builtin_amdgcn_global_load_lds(                                              \
                (const __attribute__((address_space(1))) unsigned int*)(gl_ + tid * 8),    \
                (__attribute__((address_space(3))) unsigned int*)&hb[buf][2048 + tid * 8], 16, 0, 0); \
            __builtin_amdgcn_global_load_lds(                                              \
                (const __attribute__((address_space(1))) unsigned int*)(gl_ + 1024 + tid * 8), \
                (__attribute__((address_space(3))) unsigned int*)&hb[buf][3072 + tid * 8], 16, 0, 0); \
        } while (0)

    #define MATHT(hfS, lfS)                                                                \
        do {                                                                               \
            _Pragma("unroll")                                                              \
            for (int mt = 0; mt < 2; ++mt) {                                               \
                const float E1 = mt ? E1b : E1a, F1 = mt ? F1b : F1a;                      \
                const unsigned bits = ((mt ? aw1 : aw0) >> (quad * 8)) & 0xFFu;            \
                float dd = 0.f;                                                            \
                _Pragma("unroll")                                                          \
                for (int p = 0; p < 4; ++p) {                                              \
                    float4 v = e[p];                                                       \
                    float wp0 = E1 * v.x, wn0 = F1 * v.y;                                  \
                    float w0 = ((bits >> (2 * p)) & 1u) ? (wp0 > 1.f ? wp0 : wn0) : 0.f;   \
                    float wp1 = E1 * v.z, wn1 = F1 * v.w;                                  \
                    float w1 = ((bits >> (2 * p + 1)) & 1u) ? (wp1 > 1.f ? wp1 : wn1) : 0.f; \
                    dd += w0 + w1;                                                         \
                    split_pack2(w0, w1, hfS[mt].u[p], lfS[mt].u[p]);                       \
                }                                                                          \
                if (mt) den1 += dd; else den0 += dd;                                       \
            }                                                                              \
        } while (0)

    #define MFMAT(cur, hfS, lfS)                                                           \
        do {                                                                               \
            _Pragma("unroll")                                                              \
            for (int nt = 0; nt < 4; ++nt) {                                               \
                const int f = nt * 16 + row;                                               \
                const int off = f * 32 + ((quad ^ ((f >> 1) & 3)) * 8);                    \
                bf16x8 bh = *(const bf16x8*)&hb[cur][off];                                 \
                bf16x8 bl = *(const bf16x8*)&hb[cur][2048 + off];                          \
                _Pragma("unroll")                                                          \
                for (int mt = 0; mt < 2; ++mt) {                                           \
                    acc[mt][nt] = __builtin_amdgcn_mfma_f32_16x16x32_bf16(hfS[mt].v, bh, acc[mt][nt], 0, 0, 0); \
                    acc[mt][nt] = __builtin_amdgcn_mfma_f32_16x16x32_bf16(lfS[mt].v, bh, acc[mt][nt], 0, 0, 0); \
                    acc[mt][nt] = __builtin_amdgcn_mfma_f32_16x16x32_bf16(hfS[mt].v, bl, acc[mt][nt], 0, 0, 0); \
                }                                                                          \
            }                                                                              \
        } while (0)

    LOADT(0);                                        // ef2/adj loads (oldest in vmcnt)
    STAGE(0, t0);                                    // staging issued after -> decoupled
    MATHT(hfA, lfA);                                 // waits only the ef2 loads
    for (int jt = 0; jt < njt; jt += 2) {
        __syncthreads();                             // tile jt staged in buf 0
        LOADT(jt + 1);
        STAGE(1, t0 + jt + 1);
        MFMAT(0, hfA, lfA);                          // pure LDS+MFMA, no loads
        MATHT(hfB, lfB);                             // waits ef2 only (vmcnt keeps staging)
        __syncthreads();                             // tile jt+1 staged in buf 1
        if (jt + 2 < njt) {
            LOADT(jt + 2);
            STAGE(0, t0 + jt + 2);
        }
        MFMAT(1, hfB, lfB);
        if (jt + 2 < njt) MATHT(hfA, lfA);
    }
    #undef LOADT
    #undef STAGE
    #undef MATHT
    #undef MFMAT

    // row denominators: lanes {l, l^16, l^32, l^48} share a row
    den0 += __shfl_xor(den0, 16); den0 += __shfl_xor(den0, 32);
    den1 += __shfl_xor(den1, 16); den1 += __shfl_xor(den1, 32);
    float* o = pO + (size_t)blockIdx.y * (GN * 64);
    #pragma unroll
    for (int mt = 0; mt < 2; ++mt)
        #pragma unroll
        for (int r = 0; r < 4; ++r) {
            const int grow = i0 + wv * 32 + mt * 16 + quad * 4 + r;
            #pragma unroll
            for (int nt = 0; nt < 4; ++nt)
                o[(size_t)grow * 64 + nt * 16 + row] = acc[mt][nt][r];
        }
    if (lane < 16) {
        pd[blockIdx.y * GN + i0 + wv * 32 + lane] = den0;
        pd[blockIdx.y * GN + i0 + wv * 32 + 16 + lane] = den1;
    }
}

// Fused zred2 + l2prep: combine L1 partials -> z (LDS only) -> h2 = z @ W_out
// -> ef1b/ef2b factors + swizzled bf16 image (32-j tiles). grid 64, 256 thr.
__global__ __launch_bounds__(256) void mid(const float* __restrict__ pO,
                                           const float* __restrict__ pd,
                                           const float* __restrict__ Wo,
                                           const float* __restrict__ ao,
                                           unsigned short* __restrict__ img2h,
                                           unsigned short* __restrict__ img2l,
                                           float2* __restrict__ ef1b,
                                           float2* __restrict__ ef2b) {
    __shared__ __align__(16) float zt[64 * 68];
    __shared__ float Wl[64 * 57];
    __shared__ float invd[8][64];
    const int tid = threadIdx.x;
    const int i0 = blockIdx.x * 64;
    for (int idx = tid; idx < 64 * 56; idx += 256) {
        int k = idx / 56, c = idx - k * 56;
        Wl[k * 57 + c] = Wo[idx];
    }
    for (int idx = tid; idx < 512; idx += 256) {
        int hd = idx >> 6, r = idx & 63;
        invd[hd][r] = 1.f / (pd[(2 * hd) * GN + i0 + r] + pd[(2 * hd + 1) * GN + i0 + r]);
    }
    __syncthreads();
    #pragma unroll
    for (int it = 0; it < 16; ++it) {                // z fill: 4096 elems
        int e = it * 256 + tid;
        int r = e >> 6, f = e & 63;
        size_t base = (size_t)(i0 + r) * 64 + f;
        float s = 0.f;
        #pragma unroll
        for (int hd = 0; hd < GNH; ++hd) {
            float o = pO[(size_t)(2 * hd) * (GN * 64) + base] +
                      pO[(size_t)(2 * hd + 1) * (GN * 64) + base];
            float v = o * invd[hd][r];
            s += v > 0.f ? v : FAST_EXP2(v * LOG2E) - 1.f;
        }
        zt[r * 68 + f] = s * 0.125f;
    }
    __syncthreads();
    const int rrow = tid >> 2, seg = (tid & 3) * 16;
    float hreg[16];
    #pragma unroll
    for (int c = 0; c < 16; ++c) hreg[c] = 0.f;
    for (int k0 = 0; k0 < 64; k0 += 4) {
        float4 zv = *(const float4*)&zt[rrow * 68 + k0];
        #pragma unroll
        for (int c = 0; c < 16; ++c) {
            int col = seg + c;
            if (col < 56)
                hreg[c] += zv.x * Wl[k0 * 57 + col] + zv.y * Wl[(k0 + 1) * 57 + col] +
                           zv.z * Wl[(k0 + 2) * 57 + col] + zv.w * Wl[(k0 + 3) * 57 + col];
        }
    }
    {   // row/col factors for layer 2
        float p1 = 0.f, p2 = 0.f;
        #pragma unroll
        for (int c = 0; c < 16; ++c) {
            int col = seg + c;
            if (col < 56) {
                p1 += hreg[c] * ao[col];
                p2 += hreg[c] * ao[56 + col];
            }
        }
        p1 += __shfl_xor(p1, 1); p1 += __shfl_xor(p1, 2);
        p2 += __shfl_xor(p2, 1); p2 += __shfl_xor(p2, 2);
        if ((tid & 3) == 0) {
            float t1 = p1 * LOG2E, t2 = p2 * LOG2E;
            ef1b[i0 + rrow] = make_float2(FAST_EXP2(t1), FAST_EXP2(0.2f * t1));
            ef2b[i0 + rrow] = make_float2(FAST_EXP2(t2), FAST_EXP2(0.2f * t2));
        }
    }
    __syncthreads();
    #pragma unroll
    for (int c = 0; c < 16; ++c) zt[rrow * 68 + seg + c] = (seg + c < 56) ? hreg[c] : 0.f;
    __syncthreads();
    {   // swizzled image emit (single head, 32-j tiles)
        const int f = tid >> 2;
        #pragma unroll
        for (int p = 0; p < 2; ++p) {
            int c8 = (tid & 3) * 2 + p;
            unsigned hp[4], lp[4];
            #pragma unroll
            for (int pp = 0; pp < 4; ++pp)
                split_pack2(zt[(c8 * 8 + 2 * pp) * 68 + f], zt[(c8 * 8 + 2 * pp + 1) * 68 + f],
                            hp[pp], lp[pp]);
            int t32 = c8 >> 2, c = c8 & 3;
            size_t base = ((size_t)blockIdx.x * 2 + t32) * 2048 + (size_t)f * 32;
            int off = (c ^ ((f >> 1) & 3)) * 8;
            *(uint4*)&img2h[base + off] = *(uint4*)hp;
            *(uint4*)&img2l[base + off] = *(uint4*)lp;
        }
    }
}

// combine 16 j-chunk partials, /denom, elu, softmax(56) -> out
__global__ __launch_bounds__(256) void fink2(const float* __restrict__ pO,
                                             const float* __restrict__ pd,
                                             float* __restrict__ out) {
    const int lane = threadIdx.x & 63;
    const int w = threadIdx.x >> 6;
    const int i = blockIdx.x * 4 + w;
    float o = 0.f, d = 0.f;
    #pragma unroll
    for (int c = 0; c < 16; ++c) d += pd[c * GN + i];
    if (lane < 56) {
        #pragma unroll
        for (int c = 0; c < 16; ++c) o += pO[(size_t)c * (GN * 64) + (size_t)i * 64 + lane];
    }
    float v = -1e30f;
    if (lane < 56) {
        float t = o / d;
        v = t > 0.f ? t : expm1f(t);
    }
    float m = v;
    #pragma unroll
    for (int off = 32; off; off >>= 1) m = fmaxf(m, __shfl_down(m, off));
    m = __shfl(m, 0);
    float p = (lane < 56) ? __expf(v - m) : 0.f;
    float s = p;
    #pragma unroll
    for (int off = 32; off; off >>= 1) s += __shfl_down(s, off);
    s = __shfl(s, 0);
    if (lane < 56) out[(size_t)i * 56 + lane] = p / s;
}

extern "C" void kernel_launch(void* const* d_in, const int* in_sizes, int n_in,
                              void* d_out, int out_size, void* d_ws, size_t ws_size,
                              hipStream_t stream) {
    const float* x    = (const float*)d_in[0];
    const int*   adj  = (const int*)d_in[1];
    const float* Ws   = (const float*)d_in[2];
    const float* As   = (const float*)d_in[3];
    const float* Wo   = (const float*)d_in[4];
    const float* ao   = (const float*)d_in[5];
    float* out = (float*)d_out;

    char* ws = (char*)d_ws;
    unsigned long long* adjb = (unsigned long long*)(ws + 0);           // 2 MB
    unsigned short* img1h = (unsigned short*)(ws + 2097152);            // 4 MB
    unsigned short* img1l = (unsigned short*)(ws + 6291456);            // 4 MB
    float* pO    = (float*)(ws + 10485760);                             // 16 MB (slices)
    unsigned short* x_hi = (unsigned short*)(ws + 18874368);            // 4 MB (inside pO, pre-attn only)
    unsigned short* x_lo = (unsigned short*)(ws + 23068672);            // 4 MB (inside pO, pre-attn only)
    float* pd    = (float*)(ws + 27262976);                             // 256 KB (shared L1/L2)
    float2* ef1  = (float2*)(ws + 27525120);                            // 256 KB
    float2* ef2  = (float2*)(ws + 27787264);                            // 256 KB
    unsigned short* img2h = (unsigned short*)(ws + 28049408);           // 512 KB
    unsigned short* img2l = (unsigned short*)(ws + 28573696);           // 512 KB
    float2* ef1b = (float2*)(ws + 29097984);                            // 32 KB
    float2* ef2b = (float2*)(ws + 29130752);                            // 32 KB
    unsigned short* WT_hi = (unsigned short*)(ws + 29163520);           // 512 KB
    unsigned short* WT_lo = (unsigned short*)(ws + 29687808);           // 512 KB
    // total 30212096 B ~= 28.8 MB

    prep<<<18496, 256, 0, stream>>>(adj, x, Ws, adjb, x_hi, x_lo, WT_hi, WT_lo);
    gemm_fused<<<dim3(8, 64), 256, 0, stream>>>(x_hi, x_lo, WT_hi, WT_lo, As,
                                                img1h, img1l, ef1, ef2);
    attn5<2><<<dim3(64, 16), 128, 0, stream>>>(img1h, img1l, ef1, ef2,
                                               (const unsigned*)adjb, pO, pd);
    mid<<<64, 256, 0, stream>>>(pO, pd, Wo, ao, img2h, img2l, ef1b, ef2b);
    attn5<16><<<dim3(64, 16), 128, 0, stream>>>(img2h, img2l, ef1b, ef2b,
                                                (const unsigned*)adjb, pO, pd);
    fink2<<<1024, 256, 0, stream>>>(pO, pd, out);
}